// Round 1
// baseline (28650.110 us; speedup 1.0000x reference)
//
#include <hip/hip_runtime.h>

#define B 128
#define N 64
#define D 20
#define H 256
#define WMH 1024          // WM*H
#define CAUG 21
#define SIG 231
#define C 232
#define HH 59392          // H*C
#define NSEG 63
#define HSTEP (1.0f/63.0f)
#define EPS 1e-5f

// ---------------------------------------------------------------------------
// Kernel 1: depth-2 log-signature (time-augmented, basepoint 0) + LayerNorm
// -> y (B,N,C) with y[...,0]=t, y[...,1..231]=LN(logsig)
// ---------------------------------------------------------------------------
__global__ __launch_bounds__(256) void k_logsig(const float* __restrict__ x,
                                                const float* __restrict__ sg,
                                                const float* __restrict__ sb,
                                                float* __restrict__ y) {
  __shared__ float yb[N][C];   // cols 1..231 hold logsig values
  int b = blockIdx.x, tid = threadIdx.x;
  // level-1 channels: p = [t, x]
  for (int ii = tid; ii < N * CAUG; ii += 256) {
    int n = ii / CAUG, j = ii % CAUG;
    float v = (j == 0) ? (n * (1.0f / 63.0f)) : x[(b * N + n) * D + (j - 1)];
    yb[n][1 + j] = v;
  }
  __syncthreads();
  // level-2: Levy areas for pairs i<j (np.triu_indices order), cumsum over n
  if (tid < 210) {
    int i = 0, rem = tid;
    while (rem >= (CAUG - 1) - i) { rem -= (CAUG - 1) - i; i++; }
    int j = i + 1 + rem;
    float acc = 0.f, pi_prev = 0.f, pj_prev = 0.f;
    for (int n = 0; n < N; n++) {
      float pi = yb[n][1 + i], pj = yb[n][1 + j];
      float di = pi - pi_prev, dj = pj - pj_prev;
      acc += 0.5f * (pi_prev * dj - di * pj_prev);
      yb[n][1 + CAUG + tid] = acc;   // cols 22..231, disjoint from reads (1..21)
      pi_prev = pi; pj_prev = pj;
    }
  }
  __syncthreads();
  // LayerNorm over 231 channels per row, write y
  int w = tid >> 6, l = tid & 63;
  for (int n = w; n < N; n += 4) {
    float s1 = 0.f, s2 = 0.f;
    for (int s = l; s < SIG; s += 64) { float v = yb[n][1 + s]; s1 += v; s2 += v * v; }
    for (int off = 32; off > 0; off >>= 1) { s1 += __shfl_down(s1, off); s2 += __shfl_down(s2, off); }
    s1 = __shfl(s1, 0); s2 = __shfl(s2, 0);
    float mean = s1 * (1.0f / SIG);
    float var  = s2 * (1.0f / SIG) - mean * mean;
    float rs = rsqrtf(var + EPS);
    float* yrow = y + ((size_t)b * N + n) * C;
    if (l == 0) yrow[0] = n * (1.0f / 63.0f);
    for (int s = l; s < SIG; s += 64)
      yrow[1 + s] = (yb[n][1 + s] - mean) * rs * sg[s] + sb[s];
  }
}

// ---------------------------------------------------------------------------
// Kernel 2: natural cubic spline second derivatives (constant-coef Thomas)
// -> d_knot, d_mid laid out (NSEG, B, C)
// ---------------------------------------------------------------------------
__global__ __launch_bounds__(256) void k_spline(const float* __restrict__ y,
                                                float* __restrict__ dknot,
                                                float* __restrict__ dmid) {
  __shared__ float yb[N * C];
  __shared__ float cp_s[62], id_s[62];
  int b = blockIdx.x, tid = threadIdx.x;
  for (int ii = tid; ii < N * C; ii += 256) yb[ii] = y[(size_t)b * N * C + ii];
  if (tid == 0) {
    const float a = HSTEP / 6.f, bb = 2.f * HSTEP / 3.f;
    float id0 = 1.f / bb; id_s[0] = id0; cp_s[0] = a * id0;
    for (int j = 1; j < 62; j++) {
      float den = bb - a * cp_s[j - 1];
      float idj = 1.f / den; id_s[j] = idj; cp_s[j] = a * idj;
    }
  }
  __syncthreads();
  int c = tid;
  if (c < C) {
    const float a = HSTEP / 6.f;
    float dp[62];
    dp[0] = (yb[2 * C + c] - 2.f * yb[1 * C + c] + yb[0 * C + c]) * 63.0f * id_s[0];
#pragma unroll
    for (int j = 1; j < 62; j++) {
      float rj = (yb[(j + 2) * C + c] - 2.f * yb[(j + 1) * C + c] + yb[j * C + c]) * 63.0f;
      dp[j] = (rj - a * dp[j - 1]) * id_s[j];
    }
#pragma unroll
    for (int j = 60; j >= 0; j--) dp[j] -= cp_s[j] * dp[j + 1];
    // M[0]=M[63]=0; M[i]=dp[i-1] for i=1..62
#pragma unroll
    for (int n = 0; n < NSEG; n++) {
      float Mn  = (n == 0)  ? 0.f : dp[n - 1];
      float Mn1 = (n == 62) ? 0.f : dp[n];
      float dy = (yb[(n + 1) * C + c] - yb[n * C + c]) * 63.0f;
      float dk = dy - (HSTEP / 6.f)  * (2.f * Mn + Mn1);
      float dm = dy + (HSTEP / 24.f) * (Mn - Mn1);
      dknot[((size_t)n * B + b) * C + c] = dk;
      dmid [((size_t)n * B + b) * C + c] = dm;
    }
  }
}

// ---------------------------------------------------------------------------
// Kernel 3: initial hidden state h0 = relu(x[:,0]@hW1+hb1)@hW2+hb2 -> z
// ---------------------------------------------------------------------------
__global__ __launch_bounds__(256) void k_h0(const float* __restrict__ x,
                                            const float* __restrict__ hW1,
                                            const float* __restrict__ hb1,
                                            const float* __restrict__ hW2,
                                            const float* __restrict__ hb2,
                                            float* __restrict__ z) {
  __shared__ float r[H];
  int b = blockIdx.x, tid = threadIdx.x;
  float s = hb1[tid];
#pragma unroll
  for (int d = 0; d < D; d++) s += x[(size_t)(b * N) * D + d] * hW1[d * H + tid];
  r[tid] = fmaxf(s, 0.f);
  __syncthreads();
  float s2 = hb2[tid];
  for (int k = 0; k < H; k++) s2 += r[k] * hW2[k * H + tid];
  z[b * H + tid] = s2;
}

// ---------------------------------------------------------------------------
// Kernel 4: RDEFunc MLP up to t3 = relu(...@fW3+fb3). 2 batch rows per block.
// ---------------------------------------------------------------------------
__global__ __launch_bounds__(256) void k_mlp(const float* __restrict__ zin,
    const float* __restrict__ fW1, const float* __restrict__ fb1,
    const float* __restrict__ g1,  const float* __restrict__ be1,
    const float* __restrict__ fW2, const float* __restrict__ fb2,
    const float* __restrict__ g2,  const float* __restrict__ be2,
    const float* __restrict__ fW3, const float* __restrict__ fb3,
    float* __restrict__ t3out) {
  __shared__ float zsh[2 * H];
  __shared__ float t1[2][WMH];
  __shared__ float t2[2][H];
  __shared__ float wred[4][4];
  int tid = threadIdx.x;
  int bbase = blockIdx.x * 2;
  for (int ii = tid; ii < 2 * H; ii += 256) zsh[ii] = zin[(size_t)bbase * H + ii];
  __syncthreads();
  // layer 1: (2,256)@(256,1024), thread -> 4 consecutive cols
  int c0 = tid * 4;
  float acc0[4], acc1[4];
#pragma unroll
  for (int q = 0; q < 4; q++) { float bv = fb1[c0 + q]; acc0[q] = bv; acc1[q] = bv; }
  for (int k = 0; k < H; k++) {
    float4 w = *(const float4*)(fW1 + (size_t)k * WMH + c0);
    float z0 = zsh[k], z1 = zsh[H + k];
    acc0[0] += z0 * w.x; acc0[1] += z0 * w.y; acc0[2] += z0 * w.z; acc0[3] += z0 * w.w;
    acc1[0] += z1 * w.x; acc1[1] += z1 * w.y; acc1[2] += z1 * w.z; acc1[3] += z1 * w.w;
  }
  // LN over 1024 (both batch rows)
  float s10 = 0, s20 = 0, s11 = 0, s21 = 0;
#pragma unroll
  for (int q = 0; q < 4; q++) {
    s10 += acc0[q]; s20 += acc0[q] * acc0[q];
    s11 += acc1[q]; s21 += acc1[q] * acc1[q];
  }
  for (int off = 32; off > 0; off >>= 1) {
    s10 += __shfl_down(s10, off); s20 += __shfl_down(s20, off);
    s11 += __shfl_down(s11, off); s21 += __shfl_down(s21, off);
  }
  int w = tid >> 6, l = tid & 63;
  if (l == 0) { wred[w][0] = s10; wred[w][1] = s20; wred[w][2] = s11; wred[w][3] = s21; }
  __syncthreads();
  float S10 = wred[0][0] + wred[1][0] + wred[2][0] + wred[3][0];
  float S20 = wred[0][1] + wred[1][1] + wred[2][1] + wred[3][1];
  float S11 = wred[0][2] + wred[1][2] + wred[2][2] + wred[3][2];
  float S21 = wred[0][3] + wred[1][3] + wred[2][3] + wred[3][3];
  float m0 = S10 * (1.f / WMH), v0 = S20 * (1.f / WMH) - m0 * m0, r0 = rsqrtf(v0 + EPS);
  float m1 = S11 * (1.f / WMH), v1 = S21 * (1.f / WMH) - m1 * m1, r1 = rsqrtf(v1 + EPS);
#pragma unroll
  for (int q = 0; q < 4; q++) {
    int cc = c0 + q;
    float gv = g1[cc], bv = be1[cc];
    t1[0][cc] = fmaxf((acc0[q] - m0) * r0 * gv + bv, 0.f);
    t1[1][cc] = fmaxf((acc1[q] - m1) * r1 * gv + bv, 0.f);
  }
  __syncthreads();
  // layer 2: (2,1024)@(1024,256), thread -> col tid
  float a20 = fb2[tid], a21 = a20;
  for (int k = 0; k < WMH; k++) {
    float wv = fW2[(size_t)k * H + tid];
    a20 += t1[0][k] * wv; a21 += t1[1][k] * wv;
  }
  // LN over 256
  float q10 = a20, q20 = a20 * a20, q11 = a21, q21 = a21 * a21;
  for (int off = 32; off > 0; off >>= 1) {
    q10 += __shfl_down(q10, off); q20 += __shfl_down(q20, off);
    q11 += __shfl_down(q11, off); q21 += __shfl_down(q21, off);
  }
  __syncthreads();
  if (l == 0) { wred[w][0] = q10; wred[w][1] = q20; wred[w][2] = q11; wred[w][3] = q21; }
  __syncthreads();
  float T10 = wred[0][0] + wred[1][0] + wred[2][0] + wred[3][0];
  float T20 = wred[0][1] + wred[1][1] + wred[2][1] + wred[3][1];
  float T11 = wred[0][2] + wred[1][2] + wred[2][2] + wred[3][2];
  float T21 = wred[0][3] + wred[1][3] + wred[2][3] + wred[3][3];
  float m0b = T10 * (1.f / H), v0b = T20 * (1.f / H) - m0b * m0b, r0b = rsqrtf(v0b + EPS);
  float m1b = T11 * (1.f / H), v1b = T21 * (1.f / H) - m1b * m1b, r1b = rsqrtf(v1b + EPS);
  t2[0][tid] = fmaxf((a20 - m0b) * r0b * g2[tid] + be2[tid], 0.f);
  t2[1][tid] = fmaxf((a21 - m1b) * r1b * g2[tid] + be2[tid], 0.f);
  __syncthreads();
  // layer 3: (2,256)@(256,256)
  float a30 = fb3[tid], a31 = a30;
  for (int k = 0; k < H; k++) {
    float wv = fW3[(size_t)k * H + tid];
    a30 += t2[0][k] * wv; a31 += t2[1][k] * wv;
  }
  t3out[(size_t)(bbase + 0) * H + tid] = fmaxf(a30, 0.f);
  t3out[(size_t)(bbase + 1) * H + tid] = fmaxf(a31, 0.f);
}

// ---------------------------------------------------------------------------
// Kernel 5 (hot): out[b,h] = sum_{k,c} t3[b,k]*fW4[k,h*C+c]*dX[b,c]  (+fb4 term)
// then zout[b,h] = zin[b,h] + scale*out[b,h].
// Grid (H, 2): block = (head h, batch half). Threads 256 = 8 c-groups x 32 b.
// ---------------------------------------------------------------------------
__global__ __launch_bounds__(256) void k_contract(const float* __restrict__ t3,
    const float* __restrict__ W4, const float* __restrict__ fb4,
    const float* __restrict__ dX,
    const float* __restrict__ zin, float* __restrict__ zout, float scale) {
  __shared__ __align__(16) float ws[32 * 256];   // k-tile of W4, c padded to 256
  __shared__ float t3s[64 * 33];                 // +1 pad: kills 32-way bank conflict
  __shared__ float red[2][8][32];
  int h = blockIdx.x, bbase = blockIdx.y * 64;
  int tid = threadIdx.x;
  int cg = tid >> 5, bl = tid & 31;
  float Ta0[32], Ta1[32];
#pragma unroll
  for (int j = 0; j < 32; j++) { Ta0[j] = 0.f; Ta1[j] = 0.f; }
  for (int kt = 0; kt < 8; kt++) {
    __syncthreads();
    for (int ii = tid; ii < 32 * 256; ii += 256) {
      int kk = ii >> 8, cc = ii & 255;
      ws[ii] = (cc < C) ? W4[(size_t)(kt * 32 + kk) * HH + h * C + cc] : 0.f;
    }
    for (int ii = tid; ii < 64 * 32; ii += 256) {
      int r = ii >> 5, kk = ii & 31;
      t3s[r * 33 + kk] = t3[(size_t)(bbase + r) * H + kt * 32 + kk];
    }
    __syncthreads();
#pragma unroll 4
    for (int kk = 0; kk < 32; kk++) {
      float a0 = t3s[bl * 33 + kk];
      float a1 = t3s[(bl + 32) * 33 + kk];
      const float4* wrow = (const float4*)(ws + kk * 256 + cg * 32);
#pragma unroll
      for (int jj = 0; jj < 8; jj++) {
        float4 wv = wrow[jj];
        Ta0[jj * 4 + 0] += a0 * wv.x; Ta0[jj * 4 + 1] += a0 * wv.y;
        Ta0[jj * 4 + 2] += a0 * wv.z; Ta0[jj * 4 + 3] += a0 * wv.w;
        Ta1[jj * 4 + 0] += a1 * wv.x; Ta1[jj * 4 + 1] += a1 * wv.y;
        Ta1[jj * 4 + 2] += a1 * wv.z; Ta1[jj * 4 + 3] += a1 * wv.w;
      }
    }
  }
  // fused epilogue: (T + fb4) . dX reduction over this thread's c-range
  int c0 = cg * 32;
  int b0 = bbase + bl, b1 = bbase + 32 + bl;
  float p0 = 0.f, p1 = 0.f;
#pragma unroll
  for (int j = 0; j < 32; j++) {
    if (c0 + j < C) {
      float fb = fb4[(size_t)h * C + c0 + j];
      float d0 = dX[(size_t)b0 * C + c0 + j];
      float d1 = dX[(size_t)b1 * C + c0 + j];
      p0 += (Ta0[j] + fb) * d0;
      p1 += (Ta1[j] + fb) * d1;
    }
  }
  red[0][cg][bl] = p0;
  red[1][cg][bl] = p1;
  __syncthreads();
  if (tid < 64) {
    int bs = tid >> 5, bll = tid & 31;
    float s = 0.f;
#pragma unroll
    for (int g = 0; g < 8; g++) s += red[bs][g][bll];
    int b = bbase + bs * 32 + bll;
    zout[(size_t)b * H + h] = zin[(size_t)b * H + h] + scale * s;
  }
}

// ---------------------------------------------------------------------------
// Kernel 6: output heads Y, Z and hT
// ---------------------------------------------------------------------------
__global__ __launch_bounds__(256) void k_final(const float* __restrict__ z,
    const float* __restrict__ yW1, const float* __restrict__ yb1,
    const float* __restrict__ yW2, const float* __restrict__ yb2,
    const float* __restrict__ zW1, const float* __restrict__ zb1,
    const float* __restrict__ zW2, const float* __restrict__ zb2,
    float* __restrict__ out) {
  __shared__ float ht[H];
  __shared__ float ry[128];
  __shared__ float rz[H];
  int b = blockIdx.x, tid = threadIdx.x;
  ht[tid] = z[(size_t)b * H + tid];
  __syncthreads();
  if (tid < 128) {
    float s = yb1[tid];
    for (int k = 0; k < H; k++) s += ht[k] * yW1[k * 128 + tid];
    ry[tid] = fmaxf(s, 0.f);
  }
  {
    float s = zb1[tid];
    for (int k = 0; k < H; k++) s += ht[k] * zW1[k * H + tid];
    rz[tid] = fmaxf(s, 0.f);
  }
  __syncthreads();
  if (tid < 64) {
    float sv = ry[tid] * yW2[tid] + ry[tid + 64] * yW2[tid + 64];
    for (int off = 32; off > 0; off >>= 1) sv += __shfl_down(sv, off);
    if (tid == 0) out[b] = sv + yb2[0];
  }
  if (tid < D) {
    float s = zb2[tid];
    for (int k = 0; k < H; k++) s += rz[k] * zW2[k * D + tid];
    out[B + b * D + tid] = s;
  }
  out[B + B * D + (size_t)b * H + tid] = ht[tid];
}

// ---------------------------------------------------------------------------
extern "C" void kernel_launch(void* const* d_in, const int* in_sizes, int n_in,
                              void* d_out, int out_size, void* d_ws, size_t ws_size,
                              hipStream_t stream) {
  const float* x   = (const float*)d_in[0];
  const float* hW1 = (const float*)d_in[1];
  const float* hb1 = (const float*)d_in[2];
  const float* hW2 = (const float*)d_in[3];
  const float* hb2 = (const float*)d_in[4];
  const float* fW1 = (const float*)d_in[5];
  const float* fb1 = (const float*)d_in[6];
  const float* g1  = (const float*)d_in[7];
  const float* be1 = (const float*)d_in[8];
  const float* fW2 = (const float*)d_in[9];
  const float* fb2 = (const float*)d_in[10];
  const float* g2  = (const float*)d_in[11];
  const float* be2 = (const float*)d_in[12];
  const float* fW3 = (const float*)d_in[13];
  const float* fb3 = (const float*)d_in[14];
  const float* fW4 = (const float*)d_in[15];
  const float* fb4 = (const float*)d_in[16];
  const float* yW1 = (const float*)d_in[17];
  const float* yb1 = (const float*)d_in[18];
  const float* yW2 = (const float*)d_in[19];
  const float* yb2 = (const float*)d_in[20];
  const float* zW1 = (const float*)d_in[21];
  const float* zb1 = (const float*)d_in[22];
  const float* zW2 = (const float*)d_in[23];
  const float* zb2 = (const float*)d_in[24];
  const float* sg  = (const float*)d_in[25];
  const float* sb  = (const float*)d_in[26];

  float* ws    = (float*)d_ws;
  float* y     = ws;                            // B*N*C      = 1,900,544
  float* dknot = y + (size_t)B * N * C;         // NSEG*B*C   = 1,870,848
  float* dmid  = dknot + (size_t)NSEG * B * C;  // NSEG*B*C
  float* z     = dmid + (size_t)NSEG * B * C;   // B*H
  float* zmid  = z + B * H;                     // B*H
  float* t3    = zmid + B * H;                  // B*H
  // total ~23 MB of d_ws

  hipLaunchKernelGGL(k_logsig, dim3(B), dim3(256), 0, stream, x, sg, sb, y);
  hipLaunchKernelGGL(k_spline, dim3(B), dim3(256), 0, stream, y, dknot, dmid);
  hipLaunchKernelGGL(k_h0,     dim3(B), dim3(256), 0, stream, x, hW1, hb1, hW2, hb2, z);

  for (int n = 0; n < NSEG; n++) {
    hipLaunchKernelGGL(k_mlp, dim3(64), dim3(256), 0, stream, z,
                       fW1, fb1, g1, be1, fW2, fb2, g2, be2, fW3, fb3, t3);
    hipLaunchKernelGGL(k_contract, dim3(H, 2), dim3(256), 0, stream, t3,
                       fW4, fb4, dknot + (size_t)n * B * C, z, zmid, 0.5f * HSTEP);
    hipLaunchKernelGGL(k_mlp, dim3(64), dim3(256), 0, stream, zmid,
                       fW1, fb1, g1, be1, fW2, fb2, g2, be2, fW3, fb3, t3);
    hipLaunchKernelGGL(k_contract, dim3(H, 2), dim3(256), 0, stream, t3,
                       fW4, fb4, dmid + (size_t)n * B * C, z, z, HSTEP);
  }

  hipLaunchKernelGGL(k_final, dim3(B), dim3(256), 0, stream, z,
                     yW1, yb1, yW2, yb2, zW1, zb1, zW2, zb2, (float*)d_out);
}

// Round 2
// 7659.400 us; speedup vs baseline: 3.7405x; 3.7405x over previous
//
#include <hip/hip_runtime.h>

#define B 128
#define N 64
#define D 20
#define H 256
#define WMH 1024
#define CAUG 21
#define SIG 231
#define C 232
#define CP 240          // padded C
#define KA 288          // augmented K (256 + bias row + pad)
#define NSEG 63
#define HSTEP (1.0f/63.0f)
#define EPS 1e-5f

typedef __attribute__((ext_vector_type(8))) short short8;
typedef __attribute__((ext_vector_type(4))) float f32x4;
typedef __attribute__((ext_vector_type(4))) unsigned int uint4v;

__device__ inline short f2bf(float f) {
  unsigned int u = __float_as_uint(f);
  unsigned int r = (u + 0x7fffu + ((u >> 16) & 1u)) >> 16;
  return (short)r;
}
__device__ inline float bflo(unsigned int w) { return __uint_as_float(w << 16); }
__device__ inline float bfhi(unsigned int w) { return __uint_as_float(w & 0xffff0000u); }

// ---------------------------------------------------------------------------
// Kernel 1: depth-2 log-signature + LayerNorm -> y (B,N,C)
// ---------------------------------------------------------------------------
__global__ __launch_bounds__(256) void k_logsig(const float* __restrict__ x,
                                                const float* __restrict__ sg,
                                                const float* __restrict__ sb,
                                                float* __restrict__ y) {
  __shared__ float yb[N][C];
  int b = blockIdx.x, tid = threadIdx.x;
  for (int ii = tid; ii < N * CAUG; ii += 256) {
    int n = ii / CAUG, j = ii % CAUG;
    float v = (j == 0) ? (n * (1.0f / 63.0f)) : x[(b * N + n) * D + (j - 1)];
    yb[n][1 + j] = v;
  }
  __syncthreads();
  if (tid < 210) {
    int i = 0, rem = tid;
    while (rem >= (CAUG - 1) - i) { rem -= (CAUG - 1) - i; i++; }
    int j = i + 1 + rem;
    float acc = 0.f, pi_prev = 0.f, pj_prev = 0.f;
    for (int n = 0; n < N; n++) {
      float pi = yb[n][1 + i], pj = yb[n][1 + j];
      float di = pi - pi_prev, dj = pj - pj_prev;
      acc += 0.5f * (pi_prev * dj - di * pj_prev);
      yb[n][1 + CAUG + tid] = acc;
      pi_prev = pi; pj_prev = pj;
    }
  }
  __syncthreads();
  int w = tid >> 6, l = tid & 63;
  for (int n = w; n < N; n += 4) {
    float s1 = 0.f, s2 = 0.f;
    for (int s = l; s < SIG; s += 64) { float v = yb[n][1 + s]; s1 += v; s2 += v * v; }
    for (int off = 32; off > 0; off >>= 1) { s1 += __shfl_down(s1, off); s2 += __shfl_down(s2, off); }
    s1 = __shfl(s1, 0); s2 = __shfl(s2, 0);
    float mean = s1 * (1.0f / SIG);
    float var  = s2 * (1.0f / SIG) - mean * mean;
    float rs = rsqrtf(var + EPS);
    float* yrow = y + ((size_t)b * N + n) * C;
    if (l == 0) yrow[0] = n * (1.0f / 63.0f);
    for (int s = l; s < SIG; s += 64)
      yrow[1 + s] = (yb[n][1 + s] - mean) * rs * sg[s] + sb[s];
  }
}

// ---------------------------------------------------------------------------
// Kernel 2: natural cubic spline -> d_knot, d_mid laid out (NSEG, B, CP) padded
// ---------------------------------------------------------------------------
__global__ __launch_bounds__(256) void k_spline(const float* __restrict__ y,
                                                float* __restrict__ dknot,
                                                float* __restrict__ dmid) {
  __shared__ float yb[N * C];
  __shared__ float cp_s[62], id_s[62];
  int b = blockIdx.x, tid = threadIdx.x;
  for (int ii = tid; ii < N * C; ii += 256) yb[ii] = y[(size_t)b * N * C + ii];
  if (tid == 0) {
    const float a = HSTEP / 6.f, bb = 2.f * HSTEP / 3.f;
    float id0 = 1.f / bb; id_s[0] = id0; cp_s[0] = a * id0;
    for (int j = 1; j < 62; j++) {
      float den = bb - a * cp_s[j - 1];
      float idj = 1.f / den; id_s[j] = idj; cp_s[j] = a * idj;
    }
  }
  __syncthreads();
  int c = tid;
  if (c >= 232 && c < CP) {
    for (int n = 0; n < NSEG; n++) {
      dknot[((size_t)n * B + b) * CP + c] = 0.f;
      dmid [((size_t)n * B + b) * CP + c] = 0.f;
    }
  } else if (c < 232) {
    const float a = HSTEP / 6.f;
    float dp[62];
    dp[0] = (yb[2 * C + c] - 2.f * yb[1 * C + c] + yb[0 * C + c]) * 63.0f * id_s[0];
#pragma unroll
    for (int j = 1; j < 62; j++) {
      float rj = (yb[(j + 2) * C + c] - 2.f * yb[(j + 1) * C + c] + yb[j * C + c]) * 63.0f;
      dp[j] = (rj - a * dp[j - 1]) * id_s[j];
    }
#pragma unroll
    for (int j = 60; j >= 0; j--) dp[j] -= cp_s[j] * dp[j + 1];
#pragma unroll
    for (int n = 0; n < NSEG; n++) {
      float Mn  = (n == 0)  ? 0.f : dp[n - 1];
      float Mn1 = (n == 62) ? 0.f : dp[n];
      float dy = (yb[(n + 1) * C + c] - yb[n * C + c]) * 63.0f;
      dknot[((size_t)n * B + b) * CP + c] = dy - (HSTEP / 6.f)  * (2.f * Mn + Mn1);
      dmid [((size_t)n * B + b) * CP + c] = dy + (HSTEP / 24.f) * (Mn - Mn1);
    }
  }
}

// ---------------------------------------------------------------------------
// Kernel 3: initial hidden state
// ---------------------------------------------------------------------------
__global__ __launch_bounds__(256) void k_h0(const float* __restrict__ x,
                                            const float* __restrict__ hW1,
                                            const float* __restrict__ hb1,
                                            const float* __restrict__ hW2,
                                            const float* __restrict__ hb2,
                                            float* __restrict__ z) {
  __shared__ float r[H];
  int b = blockIdx.x, tid = threadIdx.x;
  float s = hb1[tid];
#pragma unroll
  for (int d = 0; d < D; d++) s += x[(size_t)(b * N) * D + d] * hW1[d * H + tid];
  r[tid] = fmaxf(s, 0.f);
  __syncthreads();
  float s2 = hb2[tid];
  for (int k = 0; k < H; k++) s2 += r[k] * hW2[k * H + tid];
  z[b * H + tid] = s2;
}

// ---------------------------------------------------------------------------
// Prep: transpose fW4 (256 x 59392) f32 -> W4T [h*240+c][288] bf16 (k<256 part)
// ---------------------------------------------------------------------------
__global__ __launch_bounds__(256) void k_prep_t(const float* __restrict__ fW4,
                                                short* __restrict__ W4T) {
  __shared__ float tile[64][65];
  int m0 = blockIdx.x * 64, k0 = blockIdx.y * 64;
  int lane = threadIdx.x & 63, wr = threadIdx.x >> 6;
#pragma unroll
  for (int j = 0; j < 16; j++) {
    int kk = wr * 16 + j;
    tile[kk][lane] = fW4[(size_t)(k0 + kk) * 59392 + m0 + lane];
  }
  __syncthreads();
#pragma unroll
  for (int j = 0; j < 16; j++) {
    int mloc = wr * 16 + j;
    int m = m0 + mloc;
    int hh = m / 232, cc = m - hh * 232;
    W4T[((size_t)hh * CP + cc) * KA + k0 + lane] = f2bf(tile[lane][mloc]);
  }
}

// Prep: fill k'=256 (bias), k'=257..287 zeros, and c>=232 zero rows
__global__ __launch_bounds__(256) void k_prep_pad(const float* __restrict__ fb4,
                                                  short* __restrict__ W4T) {
  int idx = blockIdx.x * 256 + threadIdx.x;
  const int partA = 61440 * 32;
  if (idx < partA) {
    int row = idx >> 5, j = idx & 31;
    int hh = row / CP, cc = row - hh * CP;
    short v = 0;
    if (j == 0 && cc < 232) v = f2bf(fb4[hh * 232 + cc]);
    W4T[(size_t)row * KA + 256 + j] = v;
  } else {
    int t = idx - partA;           // < 524288
    int k = t & 255; t >>= 8;      // t < 2048
    int cc = 232 + (t & 7); int hh = t >> 3;
    W4T[((size_t)hh * CP + cc) * KA + k] = 0;
  }
}

// Prep: f32 -> bf16 flat convert
__global__ __launch_bounds__(256) void k_prep_w(const float* __restrict__ w,
                                                short* __restrict__ o, int n) {
  int i = blockIdx.x * 256 + threadIdx.x;
  if (i < n) o[i] = f2bf(w[i]);
}

// ---------------------------------------------------------------------------
// Kernel 4: RDEFunc MLP -> t3aug bf16 [b][288] (k=256 -> 1, 257.. -> 0)
// grid 128 (1 row/block), 512 threads (8 waves)
// ---------------------------------------------------------------------------
__global__ __launch_bounds__(512) void k_mlp2(const float* __restrict__ zin,
    const short* __restrict__ w1, const float* __restrict__ fb1,
    const float* __restrict__ g1, const float* __restrict__ be1,
    const short* __restrict__ w2, const float* __restrict__ fb2,
    const float* __restrict__ g2, const float* __restrict__ be2,
    const short* __restrict__ w3, const float* __restrict__ fb3,
    short* __restrict__ t3aug) {
  __shared__ float zsh[H];
  __shared__ float t1[WMH];
  __shared__ float t2[H];
  __shared__ float red[4][H];
  __shared__ float rs8[8][2];
  int b = blockIdx.x, tid = threadIdx.x;
  int lane = tid & 63, wid = tid >> 6;
  if (tid < H) zsh[tid] = zin[b * H + tid];
  __syncthreads();
  // ---- layer 1: cols n0, n0+1
  int n0 = tid * 2;
  float a0 = fb1[n0], a1 = fb1[n0 + 1];
#pragma unroll 4
  for (int k = 0; k < H; k++) {
    float zk = zsh[k];
    unsigned int w = *(const unsigned int*)(w1 + (size_t)k * WMH + n0);
    a0 = fmaf(bflo(w), zk, a0);
    a1 = fmaf(bfhi(w), zk, a1);
  }
  // LN over 1024
  {
    float s1 = a0 + a1, s2 = a0 * a0 + a1 * a1;
    for (int off = 32; off > 0; off >>= 1) { s1 += __shfl_down(s1, off); s2 += __shfl_down(s2, off); }
    if (lane == 0) { rs8[wid][0] = s1; rs8[wid][1] = s2; }
  }
  __syncthreads();
  {
    float S1 = 0, S2 = 0;
#pragma unroll
    for (int wq = 0; wq < 8; wq++) { S1 += rs8[wq][0]; S2 += rs8[wq][1]; }
    float m = S1 * (1.f / WMH), v = S2 * (1.f / WMH) - m * m, rs = rsqrtf(v + EPS);
    t1[n0]     = fmaxf((a0 - m) * rs * g1[n0]     + be1[n0],     0.f);
    t1[n0 + 1] = fmaxf((a1 - m) * rs * g1[n0 + 1] + be1[n0 + 1], 0.f);
  }
  __syncthreads();
  // ---- layer 2: thread = (kq, 2 cols)
  int kq = tid >> 7, nn = (tid & 127) * 2;
  {
    float b0 = 0.f, b1v = 0.f;
    int k0 = kq * 256;
#pragma unroll 4
    for (int k = k0; k < k0 + 256; k++) {
      float tk = t1[k];
      unsigned int w = *(const unsigned int*)(w2 + (size_t)k * H + nn);
      b0  = fmaf(bflo(w), tk, b0);
      b1v = fmaf(bfhi(w), tk, b1v);
    }
    red[kq][nn] = b0; red[kq][nn + 1] = b1v;
  }
  __syncthreads();
  float a2 = 0.f;
  if (tid < H) a2 = fb2[tid] + red[0][tid] + red[1][tid] + red[2][tid] + red[3][tid];
  {
    float s1 = (tid < H) ? a2 : 0.f, s2 = (tid < H) ? a2 * a2 : 0.f;
    for (int off = 32; off > 0; off >>= 1) { s1 += __shfl_down(s1, off); s2 += __shfl_down(s2, off); }
    __syncthreads();
    if (lane == 0) { rs8[wid][0] = s1; rs8[wid][1] = s2; }
  }
  __syncthreads();
  {
    float S1 = 0, S2 = 0;
#pragma unroll
    for (int wq = 0; wq < 8; wq++) { S1 += rs8[wq][0]; S2 += rs8[wq][1]; }
    float m = S1 * (1.f / H), v = S2 * (1.f / H) - m * m, rs = rsqrtf(v + EPS);
    if (tid < H) t2[tid] = fmaxf((a2 - m) * rs * g2[tid] + be2[tid], 0.f);
  }
  __syncthreads();
  // ---- layer 3: thread = (kq, 2 cols), K=256 -> 64 each
  {
    float b0 = 0.f, b1v = 0.f;
    int k0 = kq * 64;
#pragma unroll 4
    for (int k = k0; k < k0 + 64; k++) {
      float tk = t2[k];
      unsigned int w = *(const unsigned int*)(w3 + (size_t)k * H + nn);
      b0  = fmaf(bflo(w), tk, b0);
      b1v = fmaf(bfhi(w), tk, b1v);
    }
    red[kq][nn] = b0; red[kq][nn + 1] = b1v;
  }
  __syncthreads();
  if (tid < H) {
    float a3 = fb3[tid] + red[0][tid] + red[1][tid] + red[2][tid] + red[3][tid];
    t3aug[(size_t)b * KA + tid] = f2bf(fmaxf(a3, 0.f));
  } else if (tid < H + 32) {
    t3aug[(size_t)b * KA + 256 + (tid - H)] = (tid == H) ? (short)0x3F80 : (short)0;
  }
}

// ---------------------------------------------------------------------------
// Kernel 5 (hot, MFMA): zout[b,h] = zin[b,h] + scale * sum_c (t3aug@W4T)[b,h,c]*dX[b,c]
// grid 256 (h), 256 threads = 4 waves, each wave: rows 32w..32w+31 (2 m-tiles)
// ---------------------------------------------------------------------------
__global__ __launch_bounds__(256) void k_con2(const short* __restrict__ t3aug,
    const short* __restrict__ W4T, const float* __restrict__ dX,
    const float* __restrict__ zin, float* __restrict__ zout, float scale) {
  __shared__ short wbuf[48 * KA];          // 27648 B
  int h = blockIdx.x, tid = threadIdx.x;
  int wv = tid >> 6, lane = tid & 63;
  int lm = lane & 15, q = lane >> 4;
  // A fragments from global (t3aug is small & L2-hot)
  short8 afr[2][9];
#pragma unroll
  for (int mt = 0; mt < 2; mt++) {
    int row = 32 * wv + 16 * mt + lm;
    const short* ap = t3aug + (size_t)row * KA + q * 8;
#pragma unroll
    for (int kc = 0; kc < 9; kc++)
      afr[mt][kc] = *(const short8*)(ap + kc * 32);
  }
  float opart[2][4] = {{0.f,0.f,0.f,0.f},{0.f,0.f,0.f,0.f}};
  const short* wsrc = W4T + ((size_t)h * CP) * KA;
  // prefetch chunk 0 into regs
  uint4v st[7];
#pragma unroll
  for (int r = 0; r < 7; r++) {
    int u = tid + r * 256;
    if (u < 1728) st[r] = *(const uint4v*)(wsrc + u * 8);
  }
  for (int ct = 0; ct < 5; ct++) {
#pragma unroll
    for (int r = 0; r < 7; r++) {
      int u = tid + r * 256;
      if (u < 1728) *(uint4v*)(wbuf + u * 8) = st[r];
    }
    __syncthreads();
    if (ct < 4) {
      const short* src = wsrc + (size_t)(ct + 1) * 1728 * 8;
#pragma unroll
      for (int r = 0; r < 7; r++) {
        int u = tid + r * 256;
        if (u < 1728) st[r] = *(const uint4v*)(src + u * 8);
      }
    }
#pragma unroll
    for (int nt = 0; nt < 3; nt++) {
      f32x4 acc0 = {0.f,0.f,0.f,0.f}, acc1 = {0.f,0.f,0.f,0.f};
      const short* bp = wbuf + (nt * 16 + lm) * KA + q * 8;
#pragma unroll
      for (int kc = 0; kc < 9; kc++) {
        short8 bf = *(const short8*)(bp + kc * 32);
        acc0 = __builtin_amdgcn_mfma_f32_16x16x32_bf16(afr[0][kc], bf, acc0, 0, 0, 0);
        acc1 = __builtin_amdgcn_mfma_f32_16x16x32_bf16(afr[1][kc], bf, acc1, 0, 0, 0);
      }
      int col = (ct * 3 + nt) * 16 + lm;
#pragma unroll
      for (int mt = 0; mt < 2; mt++) {
        int rbase = 32 * wv + 16 * mt + 4 * q;
#pragma unroll
        for (int r = 0; r < 4; r++) {
          float u = (mt == 0) ? acc0[r] : acc1[r];
          opart[mt][r] += u * dX[(size_t)(rbase + r) * CP + col];
        }
      }
    }
    __syncthreads();
  }
#pragma unroll
  for (int off = 1; off < 16; off <<= 1)
#pragma unroll
    for (int mt = 0; mt < 2; mt++)
#pragma unroll
      for (int r = 0; r < 4; r++)
        opart[mt][r] += __shfl_xor(opart[mt][r], off);
  if (lm == 0) {
#pragma unroll
    for (int mt = 0; mt < 2; mt++)
#pragma unroll
      for (int r = 0; r < 4; r++) {
        int row = 32 * wv + 16 * mt + 4 * q + r;
        zout[(size_t)row * H + h] = zin[(size_t)row * H + h] + scale * opart[mt][r];
      }
  }
}

// ---------------------------------------------------------------------------
// Kernel 6: output heads
// ---------------------------------------------------------------------------
__global__ __launch_bounds__(256) void k_final(const float* __restrict__ z,
    const float* __restrict__ yW1, const float* __restrict__ yb1,
    const float* __restrict__ yW2, const float* __restrict__ yb2,
    const float* __restrict__ zW1, const float* __restrict__ zb1,
    const float* __restrict__ zW2, const float* __restrict__ zb2,
    float* __restrict__ out) {
  __shared__ float ht[H];
  __shared__ float ry[128];
  __shared__ float rz[H];
  int b = blockIdx.x, tid = threadIdx.x;
  ht[tid] = z[(size_t)b * H + tid];
  __syncthreads();
  if (tid < 128) {
    float s = yb1[tid];
    for (int k = 0; k < H; k++) s += ht[k] * yW1[k * 128 + tid];
    ry[tid] = fmaxf(s, 0.f);
  }
  {
    float s = zb1[tid];
    for (int k = 0; k < H; k++) s += ht[k] * zW1[k * H + tid];
    rz[tid] = fmaxf(s, 0.f);
  }
  __syncthreads();
  if (tid < 64) {
    float sv = ry[tid] * yW2[tid] + ry[tid + 64] * yW2[tid + 64];
    for (int off = 32; off > 0; off >>= 1) sv += __shfl_down(sv, off);
    if (tid == 0) out[b] = sv + yb2[0];
  }
  if (tid < D) {
    float s = zb2[tid];
    for (int k = 0; k < H; k++) s += rz[k] * zW2[k * D + tid];
    out[B + b * D + tid] = s;
  }
  out[B + B * D + (size_t)b * H + tid] = ht[tid];
}

// ---------------------------------------------------------------------------
extern "C" void kernel_launch(void* const* d_in, const int* in_sizes, int n_in,
                              void* d_out, int out_size, void* d_ws, size_t ws_size,
                              hipStream_t stream) {
  const float* x   = (const float*)d_in[0];
  const float* hW1 = (const float*)d_in[1];
  const float* hb1 = (const float*)d_in[2];
  const float* hW2 = (const float*)d_in[3];
  const float* hb2 = (const float*)d_in[4];
  const float* fW1 = (const float*)d_in[5];
  const float* fb1 = (const float*)d_in[6];
  const float* g1  = (const float*)d_in[7];
  const float* be1 = (const float*)d_in[8];
  const float* fW2 = (const float*)d_in[9];
  const float* fb2 = (const float*)d_in[10];
  const float* g2  = (const float*)d_in[11];
  const float* be2 = (const float*)d_in[12];
  const float* fW3 = (const float*)d_in[13];
  const float* fb3 = (const float*)d_in[14];
  const float* fW4 = (const float*)d_in[15];
  const float* fb4 = (const float*)d_in[16];
  const float* yW1 = (const float*)d_in[17];
  const float* yb1 = (const float*)d_in[18];
  const float* yW2 = (const float*)d_in[19];
  const float* yb2 = (const float*)d_in[20];
  const float* zW1 = (const float*)d_in[21];
  const float* zb1 = (const float*)d_in[22];
  const float* zW2 = (const float*)d_in[23];
  const float* zb2 = (const float*)d_in[24];
  const float* sg  = (const float*)d_in[25];
  const float* sb  = (const float*)d_in[26];

  float* ws    = (float*)d_ws;
  float* dknot = ws;                              // 63*128*240 = 1,935,360 f
  float* dmid  = dknot + (size_t)NSEG * B * CP;   // 1,935,360 f
  float* z     = dmid + (size_t)NSEG * B * CP;    // 32768 f
  float* zmid  = z + B * H;                       // 32768 f
  short* t3aug = (short*)(zmid + B * H);          // 128*288 = 36,864 s
  short* w1b   = t3aug + (size_t)B * KA;          // 262,144 s
  short* w2b   = w1b + 262144;                    // 262,144 s
  short* w3b   = w2b + 262144;                    // 65,536 s
  short* W4T   = w3b + 65536;                     // 61440*288 = 17,694,720 s
  float* y     = (float*)W4T;                     // alias: y dead before W4T built
  // total ~52.4 MB

  hipLaunchKernelGGL(k_logsig, dim3(B), dim3(256), 0, stream, x, sg, sb, y);
  hipLaunchKernelGGL(k_spline, dim3(B), dim3(256), 0, stream, y, dknot, dmid);
  hipLaunchKernelGGL(k_h0,     dim3(B), dim3(256), 0, stream, x, hW1, hb1, hW2, hb2, z);
  // y is dead now; build W4T over it
  hipLaunchKernelGGL(k_prep_t,   dim3(928, 4), dim3(256), 0, stream, fW4, W4T);
  hipLaunchKernelGGL(k_prep_pad, dim3(9728),   dim3(256), 0, stream, fb4, W4T);
  hipLaunchKernelGGL(k_prep_w,   dim3(1024),   dim3(256), 0, stream, fW1, w1b, 262144);
  hipLaunchKernelGGL(k_prep_w,   dim3(1024),   dim3(256), 0, stream, fW2, w2b, 262144);
  hipLaunchKernelGGL(k_prep_w,   dim3(256),    dim3(256), 0, stream, fW3, w3b, 65536);

  for (int n = 0; n < NSEG; n++) {
    hipLaunchKernelGGL(k_mlp2, dim3(B), dim3(512), 0, stream, z,
                       w1b, fb1, g1, be1, w2b, fb2, g2, be2, w3b, fb3, t3aug);
    hipLaunchKernelGGL(k_con2, dim3(H), dim3(256), 0, stream, t3aug,
                       W4T, dknot + (size_t)n * B * CP, z, zmid, 0.5f * HSTEP);
    hipLaunchKernelGGL(k_mlp2, dim3(B), dim3(512), 0, stream, zmid,
                       w1b, fb1, g1, be1, w2b, fb2, g2, be2, w3b, fb3, t3aug);
    hipLaunchKernelGGL(k_con2, dim3(H), dim3(256), 0, stream, t3aug,
                       W4T, dmid + (size_t)n * B * CP, z, z, HSTEP);
  }

  hipLaunchKernelGGL(k_final, dim3(B), dim3(256), 0, stream, z,
                     yW1, yb1, yW2, yb2, zW1, zb1, zW2, zb2, (float*)d_out);
}